// Round 8
// baseline (322.798 us; speedup 1.0000x reference)
//
#include <hip/hip_runtime.h>
#include <hip/hip_bf16.h>

// LinearCrossAttention fused pipeline for MI355X (gfx950).
// Algebra: conv1x1 commutes with resize; Wo folds into V (Wov=Wo*Wv, bov=Wo*bv):
//   y = f_geo + bo + (M*Q)/norm,  M[o][c] = sum_p V2[o][p] K[c][p].
// R8: kill drain-latency -- stage FULL K=256 operands per barrier (chunk-major
// [r][32] subtiles, unchanged MFMA frag reads), 2 drains per 64x64 GEMM block,
// ~17 per k_fuse block (was ~48). 64x64 tiles give semconv grid 1024.

#define B_ 8
#define C_ 256
#define N_ 4096
#define NS_ 1024
#define KVCH 16

typedef unsigned short u16;
using bf16x8 = __attribute__((ext_vector_type(8))) short;
using f32x4 = __attribute__((ext_vector_type(4))) float;

__device__ inline u16 f2bf(float f) {
  unsigned u = __builtin_bit_cast(unsigned, f);
  unsigned r = (u + 0x7fffu + ((u >> 16) & 1u)) >> 16;
  return (u16)r;
}
__device__ inline float bf2f(u16 x) {
  return __builtin_bit_cast(float, ((unsigned)x) << 16);
}
__device__ __forceinline__ void gl_lds16(const u16* g, u16* l) {
  __builtin_amdgcn_global_load_lds((const __attribute__((address_space(1))) void*)g,
                                   (__attribute__((address_space(3))) void*)l, 16, 0, 0);
}

// ---- 64x64 NT GEMM, K=256 as two 128-slabs, 2 drains total ----
// LDS: A@lds[0..8192), B@lds[8192..16384) (u16 elems). Chunk-major [64][32].
__device__ inline void gemm64(const u16* __restrict__ A, const u16* __restrict__ Bm,
                              int lda, int ldb, int k0,
                              u16* __restrict__ lds, f32x4 (&acc)[2][2])
{
  const int t = threadIdx.x, lane = t & 63, w = t >> 6;
  const int wr = w >> 1, wc = w & 1, lr = lane & 15;
  const int lg = lane >> 4;
  const int srow = w * 16 + (lane >> 2), scol = (lane & 3) * 8;
  u16* Alds = lds;
  u16* Blds = lds + 8192;
  for (int slab = 0; slab < 2; ++slab) {
    const int kb = k0 + slab * 128;
#pragma unroll
    for (int i = 0; i < 4; ++i)
      gl_lds16(A + (size_t)srow * lda + kb + i * 32 + scol, Alds + i * 2048 + w * 512);
#pragma unroll
    for (int i = 0; i < 4; ++i)
      gl_lds16(Bm + (size_t)srow * ldb + kb + i * 32 + scol, Blds + i * 2048 + w * 512);
    __syncthreads();
#pragma unroll
    for (int ch = 0; ch < 4; ++ch) {
      const u16* ap = Alds + ch * 2048 + (wr * 32 + lr) * 32 + lg * 8;
      const u16* bp = Blds + ch * 2048 + (wc * 32 + lr) * 32 + lg * 8;
      bf16x8 af[2], bf[2];
      af[0] = *(const bf16x8*)ap; af[1] = *(const bf16x8*)(ap + 16 * 32);
      bf[0] = *(const bf16x8*)bp; bf[1] = *(const bf16x8*)(bp + 16 * 32);
#pragma unroll
      for (int m = 0; m < 2; ++m)
#pragma unroll
        for (int n = 0; n < 2; ++n)
          acc[m][n] = __builtin_amdgcn_mfma_f32_16x16x32_bf16(af[m], bf[n], acc[m][n], 0, 0, 0);
    }
    __syncthreads();
  }
}

// ---- prep ----
__global__ __launch_bounds__(256) void k_transpose_cast(const float* __restrict__ in,
                                                        u16* __restrict__ out, int rows, int cols)
{
  __shared__ float tile[32][33];
  int b = blockIdx.z;
  const float* src = in + (size_t)b * rows * cols;
  u16* dst = out + (size_t)b * rows * cols;
  int c0 = blockIdx.x * 32, r0 = blockIdx.y * 32;
  int tx = threadIdx.x & 31, ty = threadIdx.x >> 5;
#pragma unroll
  for (int i = 0; i < 32; i += 8)
    tile[ty + i][tx] = src[(size_t)(r0 + ty + i) * cols + (c0 + tx)];
  __syncthreads();
#pragma unroll
  for (int i = 0; i < 32; i += 8)
    dst[(size_t)(c0 + ty + i) * rows + (r0 + tx)] = f2bf(tile[tx][ty + i]);
}

__global__ __launch_bounds__(256) void k_cast3(const float* __restrict__ wq, const float* __restrict__ wk,
                                               const float* __restrict__ wo,
                                               u16* oq, u16* ok, u16* oo,
                                               const float* __restrict__ bv, float* __restrict__ bov,
                                               float* __restrict__ stats)
{
  int i = blockIdx.x * 256 + threadIdx.x;
  oq[i] = f2bf(wq[i]); ok[i] = f2bf(wk[i]); oo[i] = f2bf(wo[i]);
  if (i < 16) stats[i] = 0.f;
  if (blockIdx.x == 255) {
    int o = threadIdx.x;
    float s = 0.f;
    for (int d = 0; d < C_; ++d) s += wo[o * C_ + d] * bv[d];
    bov[o] = s;
  }
}

// ---- Wov = Wo * Wv (B = WvT) ----
__global__ __launch_bounds__(256) void k_wov(const u16* __restrict__ Wob, const u16* __restrict__ WvT,
                                             u16* __restrict__ Wov)
{
  __shared__ __align__(16) char smem[32768];
  u16* glds = (u16*)smem;
  float* eplds = (float*)smem;  // [64][68], alias after GEMM
  int tn = blockIdx.x, tm = blockIdx.y;
  f32x4 acc[2][2] = {};
  gemm64(Wob + (size_t)tm * 64 * C_, WvT + (size_t)tn * 64 * C_, C_, C_, 0, glds, acc);
  int t = threadIdx.x, lane = t & 63, w = t >> 6;
  int wr = w >> 1, wc = w & 1, lr = lane & 15, lg = lane >> 4;
#pragma unroll
  for (int m = 0; m < 2; ++m)
#pragma unroll
    for (int n = 0; n < 2; ++n)
#pragma unroll
      for (int r = 0; r < 4; ++r)
        eplds[(wr * 32 + m * 16 + lg * 4 + r) * 68 + wc * 32 + n * 16 + lr] = acc[m][n][r];
  __syncthreads();
#pragma unroll
  for (int rd = 0; rd < 4; ++rd) {
    int rloc = rd * 16 + (t >> 4), cloc = (t & 15) * 4;
    float4 a = *(const float4*)&eplds[rloc * 68 + cloc];
    ushort4 o;
    o.x = f2bf(a.x); o.y = f2bf(a.y); o.z = f2bf(a.z); o.w = f2bf(a.w);
    *(ushort4*)&Wov[(size_t)(tm * 64 + rloc) * C_ + tn * 64 + cloc] = o;
  }
}

// ---- K / V2 conv at 32x32 (64x64 tiles, grid 1024) ----
__global__ __launch_bounds__(256) void k_semconv(const u16* __restrict__ fsemT,
                                                 const u16* __restrict__ Wk, const u16* __restrict__ Wov,
                                                 const float* __restrict__ bk, const float* __restrict__ bov,
                                                 u16* __restrict__ Kpre, u16* __restrict__ V2pre)
{
  __shared__ __align__(16) char smem[32768];
  u16* glds = (u16*)smem;
  float* eplds = (float*)smem;
  int b = blockIdx.z >> 1, sel = blockIdx.z & 1;
  int m0 = blockIdx.y * 64, n0 = blockIdx.x * 64;
  const u16* A = (sel ? Wov : Wk) + (size_t)m0 * C_;
  const u16* Bm = fsemT + (size_t)b * NS_ * C_ + (size_t)n0 * C_;
  const float* bias = sel ? bov : bk;
  u16* out = (sel ? V2pre : Kpre) + (size_t)b * C_ * NS_;
  f32x4 acc[2][2] = {};
  gemm64(A, Bm, C_, C_, 0, glds, acc);
  int t = threadIdx.x, lane = t & 63, w = t >> 6;
  int wr = w >> 1, wc = w & 1, lr = lane & 15, lg = lane >> 4;
#pragma unroll
  for (int m = 0; m < 2; ++m)
#pragma unroll
    for (int n = 0; n < 2; ++n)
#pragma unroll
      for (int r = 0; r < 4; ++r)
        eplds[(wr * 32 + m * 16 + lg * 4 + r) * 68 + wc * 32 + n * 16 + lr] = acc[m][n][r];
  __syncthreads();
#pragma unroll
  for (int rd = 0; rd < 4; ++rd) {
    int rloc = rd * 16 + (t >> 4), cloc = (t & 15) * 4;
    int row = m0 + rloc;
    float4 a = *(const float4*)&eplds[rloc * 68 + cloc];
    float bi = bias[row];
    ushort4 o;
    o.x = f2bf(a.x + bi); o.y = f2bf(a.y + bi); o.z = f2bf(a.z + bi); o.w = f2bf(a.w + bi);
    *(ushort4*)&out[(size_t)row * NS_ + n0 + cloc] = o;
  }
}

// ---- bilinear 2x upsample; phi+Ksum on K planes ----
__global__ __launch_bounds__(256) void k_resize(const u16* __restrict__ Kpre, const u16* __restrict__ V2pre,
                                                u16* __restrict__ Kbf, u16* __restrict__ V2bf,
                                                float* __restrict__ Ksum)
{
  int sel = blockIdx.y;
  const u16* src = (sel ? V2pre : Kpre) + (size_t)blockIdx.x * NS_;
  u16* dst = (sel ? V2bf : Kbf) + (size_t)blockIdx.x * N_;
  float s = 0.f;
  for (int i = threadIdx.x; i < N_; i += 256) {
    int yy = i >> 6, xx = i & 63;
    int yh = yy >> 1, xh = xx >> 1;
    int ys0, ys1, xs0, xs1; float wy0, wy1, wx0, wx1;
    if (yy & 1) { ys0 = yh; ys1 = yh < 31 ? yh + 1 : 31; wy0 = 0.75f; wy1 = 0.25f; }
    else        { ys0 = yh > 0 ? yh - 1 : 0; ys1 = yh;   wy0 = 0.25f; wy1 = 0.75f; }
    if (xx & 1) { xs0 = xh; xs1 = xh < 31 ? xh + 1 : 31; wx0 = 0.75f; wx1 = 0.25f; }
    else        { xs0 = xh > 0 ? xh - 1 : 0; xs1 = xh;   wx0 = 0.25f; wx1 = 0.75f; }
    float r0 = wx0 * bf2f(src[ys0 * 32 + xs0]) + wx1 * bf2f(src[ys0 * 32 + xs1]);
    float r1 = wx0 * bf2f(src[ys1 * 32 + xs0]) + wx1 * bf2f(src[ys1 * 32 + xs1]);
    float v = wy0 * r0 + wy1 * r1;
    if (!sel) { v = v > 0.f ? v + 1.f : __expf(v); s += v; }
    dst[i] = f2bf(v);
  }
  if (!sel) {
    __shared__ float red[256];
    red[threadIdx.x] = s; __syncthreads();
    for (int off = 128; off > 0; off >>= 1) {
      if (threadIdx.x < off) red[threadIdx.x] += red[threadIdx.x + off];
      __syncthreads();
    }
    if (threadIdx.x == 0) Ksum[blockIdx.x] = red[0];
  }
}

// ---- M split-K partials: 64x64 tiles, 16 p-chunks of 256 ----
__global__ __launch_bounds__(256) void k_kv(const u16* __restrict__ V2bf, const u16* __restrict__ Kbf,
                                            float* __restrict__ Mpart)
{
  __shared__ __align__(16) char smem[32768];
  u16* glds = (u16*)smem;
  float* eplds = (float*)smem;
  int tn = blockIdx.x, tm = blockIdx.y;
  int b = blockIdx.z >> 4, ch = blockIdx.z & 15;
  const u16* A = V2bf + (size_t)b * C_ * N_ + (size_t)tm * 64 * N_;
  const u16* Bm = Kbf + (size_t)b * C_ * N_ + (size_t)tn * 64 * N_;
  f32x4 acc[2][2] = {};
  gemm64(A, Bm, N_, N_, ch * 256, glds, acc);
  float* out = Mpart + ((size_t)(b * 16 + ch) * 16 + tm * 4 + tn) * 4096;
  int t = threadIdx.x, lane = t & 63, w = t >> 6;
  int wr = w >> 1, wc = w & 1, lr = lane & 15, lg = lane >> 4;
#pragma unroll
  for (int m = 0; m < 2; ++m)
#pragma unroll
    for (int n = 0; n < 2; ++n)
#pragma unroll
      for (int r = 0; r < 4; ++r)
        eplds[(wr * 32 + m * 16 + lg * 4 + r) * 68 + wc * 32 + n * 16 + lr] = acc[m][n][r];
  __syncthreads();
#pragma unroll
  for (int rd = 0; rd < 4; ++rd) {
    int rloc = rd * 16 + (t >> 4), cloc = (t & 15) * 4;
    float4 a = *(const float4*)&eplds[rloc * 68 + cloc];
    *(float4*)&out[rloc * 64 + cloc] = a;
  }
}

// ---- reduce partials -> Mbf[o][c] bf16 (vectorized x4) ----
__global__ __launch_bounds__(256) void k_kvred(const float* __restrict__ Mpart, u16* __restrict__ Mbf)
{
  int q = blockIdx.x * 256 + threadIdx.x;  // B*C*C/4 = 131072
  int b = q >> 14;
  int rem = q & 16383;
  int o = rem >> 6;
  int c0 = (rem & 63) * 4;
  int tile = ((o >> 6) << 2) + (c0 >> 6);
  int loc = (o & 63) * 64 + (c0 & 63);
  const float* base = Mpart + (size_t)b * 16 * 16 * 4096 + (size_t)tile * 4096 + loc;
  float4 s = {0.f, 0.f, 0.f, 0.f};
#pragma unroll
  for (int ch = 0; ch < KVCH; ++ch) {
    float4 v = *(const float4*)(base + (size_t)ch * 16 * 4096);
    s.x += v.x; s.y += v.y; s.z += v.z; s.w += v.w;
  }
  ushort4 out;
  out.x = f2bf(s.x); out.y = f2bf(s.y); out.z = f2bf(s.z); out.w = f2bf(s.w);
  *(ushort4*)&Mbf[(size_t)q * 4] = out;
}

// ---- MEGA-FUSE per (32-n-tile, b): Q=phi(fgeoT*Wq+bq) in LDS, norm in-block,
//      y = f_geo + bo + (M*Q)/norm, GN stats. ~17 drains/block. ----
__global__ __launch_bounds__(256) void k_fuse(const u16* __restrict__ fgeoT, const u16* __restrict__ Wqb,
                                              const float* __restrict__ bq, const float* __restrict__ Ksum,
                                              const u16* __restrict__ Mbf,
                                              const float* __restrict__ fgeo, const float* __restrict__ bo,
                                              float* __restrict__ y, float* __restrict__ stats)
{
  // layout (bytes): Qlds [32][264] u16 @0 (33792) | Ast 16384 @33792 | Bst 16384 @50176
  //                 normLds 128 @66560 ; eplds [32][36] f32 aliases Ast (ph2)
  __shared__ __align__(16) char smem[66688];
  u16* Qlds = (u16*)smem;
  u16* Ast = (u16*)(smem + 33792);
  u16* Bst = (u16*)(smem + 50176);
  float* normLds = (float*)(smem + 66560);
  float* eplds = (float*)(smem + 33792);
  const int t = threadIdx.x, lane = t & 63, w = t >> 6;
  const int wr = w >> 1, wc = w & 1, lr = lane & 15, lg = lane >> 4;
  const int sr2 = (w & 1) * 16 + (lane >> 2);  // stage32: row
  const int sch2 = w >> 1;                     // chunk parity
  const int scol = (lane & 3) * 8;
  const int n0 = blockIdx.x * 32, b = blockIdx.y;
  if (t < 32) normLds[t] = 1e-6f;

  // stage a [32][256] bf16 tile (16KB) chunk-major; 4 calls, dest chunk ch @ ch*1024 elems
  auto stage32 = [&](const u16* g, u16* dst) {
#pragma unroll
    for (int i = 0; i < 4; ++i)
      gl_lds16(g + (size_t)sr2 * C_ + (2 * i + sch2) * 32 + scol, dst + i * 2048 + w * 512);
  };

  stage32(fgeoT + (size_t)b * N_ * C_ + (size_t)n0 * C_, Ast);
  stage32(Wqb, Bst);
  __syncthreads();

  float bqv[8], ksv[8];
#pragma unroll
  for (int cc = 0; cc < 8; ++cc) {
    int c = cc * 32 + wc * 16 + lr;
    bqv[cc] = bq[c];
    ksv[cc] = Ksum[b * C_ + c];
  }
  // hoist A-frags (reused across all 8 cc)
  bf16x8 af[8];
#pragma unroll
  for (int ch = 0; ch < 8; ++ch)
    af[ch] = *(const bf16x8*)(Ast + ch * 1024 + (wr * 16 + lr) * 32 + lg * 8);

  // ---- phase 1: Q[32n][256c] -> Qlds, norm -> normLds ----
  for (int cc = 0; cc < 8; ++cc) {
    f32x4 a1 = {0.f, 0.f, 0.f, 0.f};
#pragma unroll
    for (int ch = 0; ch < 8; ++ch) {
      bf16x8 bf = *(const bf16x8*)(Bst + ch * 1024 + (wc * 16 + lr) * 32 + lg * 8);
      a1 = __builtin_amdgcn_mfma_f32_16x16x32_bf16(af[ch], bf, a1, 0, 0, 0);
    }
#pragma unroll
    for (int rr = 0; rr < 4; ++rr) {
      int n = wr * 16 + lg * 4 + rr;
      float v = a1[rr] + bqv[cc];
      v = v > 0.f ? v + 1.f : __expf(v);
      Qlds[n * 264 + cc * 32 + wc * 16 + lr] = f2bf(v);
      float pn = v * ksv[cc];
      pn += __shfl_xor(pn, 1); pn += __shfl_xor(pn, 2);
      pn += __shfl_xor(pn, 4); pn += __shfl_xor(pn, 8);
      if (lr == 0) atomicAdd(&normLds[n], pn);
    }
    __syncthreads();  // all waves done reading Bst
    if (cc < 7) {
      stage32(Wqb + (size_t)(cc + 1) * 32 * C_, Bst);
      __syncthreads();
    }
  }

  // ---- phase 2: y[256o][32n] in 8 o-chunks ----
  // hoist Q-frags (reused across all oh)
  __syncthreads();  // Qlds + normLds complete, visible
  bf16x8 qf[8];
#pragma unroll
  for (int ch = 0; ch < 8; ++ch)
    qf[ch] = *(const bf16x8*)&Qlds[(wc * 16 + lr) * 264 + ch * 32 + lg * 8];

  const float* fg = fgeo + (size_t)b * C_ * N_;
  float* yb = y + (size_t)b * C_ * N_;
  float ssum = 0.f, ssq = 0.f;
  for (int oh = 0; oh < 8; ++oh) {
    stage32(Mbf + (size_t)b * C_ * C_ + (size_t)oh * 32 * C_, Bst);
    __syncthreads();  // M ready (also fences prev eplds read vs this write)
    f32x4 a2 = {0.f, 0.f, 0.f, 0.f};
#pragma unroll
    for (int ch = 0; ch < 8; ++ch) {
      bf16x8 mf = *(const bf16x8*)(Bst + ch * 1024 + (wr * 16 + lr) * 32 + lg * 8);
      a2 = __builtin_amdgcn_mfma_f32_16x16x32_bf16(mf, qf[ch], a2, 0, 0, 0);
    }
#pragma unroll
    for (int rr = 0; rr < 4; ++rr)
      eplds[(wr * 16 + lg * 4 + rr) * 36 + wc * 16 + lr] = a2[rr];
    __syncthreads();
    {
      int rloc = t >> 3, cloc = (t & 7) * 4;
      int o = oh * 32 + rloc;
      float4 a = *(const float4*)&eplds[rloc * 36 + cloc];
      float4 nv = *(const float4*)&normLds[cloc];
      float4 f = *(const float4*)&fg[(size_t)o * N_ + n0 + cloc];
      float bov2 = bo[o];
      float4 v;
      v.x = f.x + bov2 + a.x / nv.x;
      v.y = f.y + bov2 + a.y / nv.y;
      v.z = f.z + bov2 + a.z / nv.z;
      v.w = f.w + bov2 + a.w / nv.w;
      *(float4*)&yb[(size_t)o * N_ + n0 + cloc] = v;
      ssum += v.x + v.y + v.z + v.w;
      ssq += v.x * v.x + v.y * v.y + v.z * v.z + v.w * v.w;
    }
  }
#pragma unroll
  for (int off = 1; off < 64; off <<= 1) {
    ssum += __shfl_xor(ssum, off);
    ssq += __shfl_xor(ssq, off);
  }
  if (lane == 0) {
    atomicAdd(&stats[b * 2], ssum);
    atomicAdd(&stats[b * 2 + 1], ssq);
  }
}

// ---- GN affine apply ----
__global__ __launch_bounds__(256) void k_gn(float* __restrict__ y, const float* __restrict__ stats,
                                            const float* __restrict__ gnw, const float* __restrict__ gnb)
{
  int idx = blockIdx.x * 256 + threadIdx.x;
  int elem = idx * 8;
  int b = elem >> 20;
  int o = (elem >> 12) & 255;
  const float cnt = (float)C_ * (float)N_;
  float mu = stats[b * 2] / cnt;
  float var = stats[b * 2 + 1] / cnt - mu * mu;
  float rs = rsqrtf(var + 1e-5f);
  float sc = gnw[o] * rs;
  float sh = gnb[o] - mu * sc;
  float4* p = reinterpret_cast<float4*>(y) + idx * 2;
  float4 v0 = p[0], v1 = p[1];
  v0.x = v0.x * sc + sh; v0.y = v0.y * sc + sh; v0.z = v0.z * sc + sh; v0.w = v0.w * sc + sh;
  v1.x = v1.x * sc + sh; v1.y = v1.y * sc + sh; v1.z = v1.z * sc + sh; v1.w = v1.w * sc + sh;
  p[0] = v0; p[1] = v1;
}

extern "C" void kernel_launch(void* const* d_in, const int* in_sizes, int n_in,
                              void* d_out, int out_size, void* d_ws, size_t ws_size,
                              hipStream_t stream)
{
  const float* f_geo = (const float*)d_in[0];
  const float* f_sem = (const float*)d_in[1];
  const float* Wq = (const float*)d_in[2];
  const float* bq = (const float*)d_in[3];
  const float* Wk = (const float*)d_in[4];
  const float* bk = (const float*)d_in[5];
  const float* Wv = (const float*)d_in[6];
  const float* bv = (const float*)d_in[7];
  const float* Wo = (const float*)d_in[8];
  const float* bo = (const float*)d_in[9];
  const float* gnw = (const float*)d_in[10];
  const float* gnb = (const float*)d_in[11];
  float* y = (float*)d_out;

  char* w = (char*)d_ws;
  auto alloc = [&](size_t bytes) { char* p = w; w += (bytes + 255) & ~(size_t)255; return p; };
  u16* fsemT = (u16*)alloc((size_t)B_ * NS_ * C_ * 2);
  u16* fgeoT = (u16*)alloc((size_t)B_ * N_ * C_ * 2);
  u16* Wqb = (u16*)alloc(65536 * 2);
  u16* Wkb = (u16*)alloc(65536 * 2);
  u16* Wob = (u16*)alloc(65536 * 2);
  u16* WvT = (u16*)alloc(65536 * 2);
  u16* Wov = (u16*)alloc(65536 * 2);
  float* bov = (float*)alloc(C_ * 4);
  u16* Kpre = (u16*)alloc((size_t)B_ * C_ * NS_ * 2);
  u16* V2pre = (u16*)alloc((size_t)B_ * C_ * NS_ * 2);
  u16* Kbf = (u16*)alloc((size_t)B_ * C_ * N_ * 2);
  u16* V2bf = (u16*)alloc((size_t)B_ * C_ * N_ * 2);
  float* Ksum = (float*)alloc((size_t)B_ * C_ * 4);
  float* Mpart = (float*)alloc((size_t)B_ * 16 * 16 * 4096 * 4);
  u16* Mbf = (u16*)alloc((size_t)B_ * C_ * C_ * 2);
  float* stats = (float*)alloc(256);

  k_transpose_cast<<<dim3(NS_ / 32, C_ / 32, B_), 256, 0, stream>>>(f_sem, fsemT, C_, NS_);
  k_transpose_cast<<<dim3(N_ / 32, C_ / 32, B_), 256, 0, stream>>>(f_geo, fgeoT, C_, N_);
  k_transpose_cast<<<dim3(C_ / 32, C_ / 32, 1), 256, 0, stream>>>(Wv, WvT, C_, C_);
  k_cast3<<<dim3(256), 256, 0, stream>>>(Wq, Wk, Wo, Wqb, Wkb, Wob, bv, bov, stats);
  k_wov<<<dim3(4, 4), 256, 0, stream>>>(Wob, WvT, Wov);
  k_semconv<<<dim3(16, 4, 16), 256, 0, stream>>>(fsemT, Wkb, Wov, bk, bov, Kpre, V2pre);
  k_resize<<<dim3(B_ * C_, 2), 256, 0, stream>>>(Kpre, V2pre, Kbf, V2bf, Ksum);
  k_kv<<<dim3(4, 4, B_ * 16), 256, 0, stream>>>(V2bf, Kbf, Mpart);
  k_kvred<<<dim3(512), 256, 0, stream>>>(Mpart, Mbf);
  k_fuse<<<dim3(N_ / 32, B_), 256, 0, stream>>>(fgeoT, Wqb, bq, Ksum, Mbf, f_geo, bo, y, stats);
  k_gn<<<dim3(B_ * C_ * N_ / 8 / 256), 256, 0, stream>>>(y, stats, gnw, gnb);
}